// Round 3
// baseline (724.707 us; speedup 1.0000x reference)
//
#include <hip/hip_runtime.h>
#include <hip/hip_bf16.h>

#define N_PTS 16384
#define DIMF  128
#define KNB   16
#define GRES  16
#define NCELL (GRES*GRES*GRES)

typedef __attribute__((ext_vector_type(8))) short bf16x8;
typedef __attribute__((ext_vector_type(4))) float f32x4;

__device__ __forceinline__ unsigned short f2b(float f){
  unsigned int u = __float_as_uint(f);
  u = u + 0x7fffu + ((u >> 16) & 1u);
  return (unsigned short)(u >> 16);
}

// ---------------- KNN: grid build ----------------
__global__ __launch_bounds__(256) void count_kernel(const float* __restrict__ pos, int* __restrict__ cnt){
  int i = blockIdx.x*256 + threadIdx.x;
  float px = pos[i*3+0], py = pos[i*3+1], pz = pos[i*3+2];
  int cx = min(GRES-1, max(0,(int)(px*(float)GRES)));
  int cy = min(GRES-1, max(0,(int)(py*(float)GRES)));
  int cz = min(GRES-1, max(0,(int)(pz*(float)GRES)));
  atomicAdd(&cnt[(cz*GRES+cy)*GRES+cx], 1);
}

__global__ __launch_bounds__(256) void scan_kernel(const int* __restrict__ cnt, int* __restrict__ starts, int* __restrict__ fillp){
  __shared__ int part[256];
  int t = threadIdx.x;
  int loc[16];
  int s = 0;
  #pragma unroll
  for (int i=0;i<16;++i){ loc[i] = s; s += cnt[t*16+i]; }
  part[t] = s;
  __syncthreads();
  if (t == 0){
    int acc = 0;
    for (int i=0;i<256;++i){ int tmp = part[i]; part[i] = acc; acc += tmp; }
  }
  __syncthreads();
  int b = part[t];
  #pragma unroll
  for (int i=0;i<16;++i){ int v = b + loc[i]; starts[t*16+i] = v; fillp[t*16+i] = v; }
}

// sq stored numpy-style: ((x*x + y*y) + z*z), each op separately f32-rounded (no contraction)
__global__ __launch_bounds__(256) void scatter_kernel(const float* __restrict__ pos, int* __restrict__ fillp,
                                                      float4* __restrict__ pos4, int* __restrict__ pidx){
  int i = blockIdx.x*256 + threadIdx.x;
  float px = pos[i*3+0], py = pos[i*3+1], pz = pos[i*3+2];
  int cx = min(GRES-1, max(0,(int)(px*(float)GRES)));
  int cy = min(GRES-1, max(0,(int)(py*(float)GRES)));
  int cz = min(GRES-1, max(0,(int)(pz*(float)GRES)));
  int c = (cz*GRES+cy)*GRES+cx;
  float sq = __fadd_rn(__fadd_rn(__fmul_rn(px,px), __fmul_rn(py,py)), __fmul_rn(pz,pz));
  int s = atomicAdd(&fillp[c], 1);
  pos4[s] = make_float4(px, py, pz, sq);
  pidx[s] = i;
}

// exact top-16 by (d2, idx) lex, d2 replicating numpy float32 bit-exactly:
//   sq: ((x2+y2)+z2) separate roundings (numpy sum, no fma)
//   dot: ascending-k FMA chain (BLAS sgemm K=3 microkernel)
//   d2 = fsub(fadd(sq_i, sq_j), fmul(2, dot))
__global__ __launch_bounds__(256) void knn_query(const float4* __restrict__ pos4, const int* __restrict__ pidx,
                                                 const int* __restrict__ starts, const int* __restrict__ cnt,
                                                 int* __restrict__ ind){
  int t = blockIdx.x*256 + threadIdx.x;
  float4 qp = pos4[t];
  int row = pidx[t];
  float qx = qp.x, qy = qp.y, qz = qp.z, qsq = qp.w;
  int cx = min(GRES-1, max(0,(int)(qx*(float)GRES)));
  int cy = min(GRES-1, max(0,(int)(qy*(float)GRES)));
  int cz = min(GRES-1, max(0,(int)(qz*(float)GRES)));
  float bd[KNB]; int bi[KNB];
  #pragma unroll
  for (int k=0;k<KNB;++k){ bd[k] = 3.0e38f; bi[k] = 0x7fffffff; }
  const double cinv = 1.0/(double)GRES;   // exact (power of 2)
  for (int r = 0; r < GRES; ++r){
    int zlo = max(0, cz-r), zhi = min(GRES-1, cz+r);
    int ylo = max(0, cy-r), yhi = min(GRES-1, cy+r);
    int xlo = max(0, cx-r), xhi = min(GRES-1, cx+r);
    for (int zz = zlo; zz <= zhi; ++zz){
      for (int yy = ylo; yy <= yhi; ++yy){
        for (int xx = xlo; xx <= xhi; ++xx){
          int ring = max(abs(zz-cz), max(abs(yy-cy), abs(xx-cx)));
          if (ring != r) continue;
          int c = (zz*GRES+yy)*GRES+xx;
          int s0 = starts[c], e = s0 + cnt[c];
          for (int s = s0; s < e; ++s){
            float4 pc = pos4[s];
            int idx = pidx[s];
            float dot = __fmaf_rn(qz, pc.z, __fmaf_rn(qy, pc.y, __fmul_rn(qx, pc.x)));
            float d   = __fsub_rn(__fadd_rn(qsq, pc.w), __fmul_rn(2.0f, dot));
            bool adm = (d < bd[KNB-1]) || (d == bd[KNB-1] && idx < bi[KNB-1]);
            if (adm){
              #pragma unroll
              for (int p = KNB-1; p >= 1; --p){
                float pd = bd[p-1]; int pi = bi[p-1];
                bool sh  = (pd > d) || (pd == d && pi > idx);
                bool ins = (!sh) && ((bd[p] > d) || (bd[p] == d && bi[p] > idx));
                bd[p] = sh ? pd : (ins ? d   : bd[p]);
                bi[p] = sh ? pi : (ins ? idx : bi[p]);
              }
              bool s0b = (bd[0] > d) || (bd[0] == d && bi[0] > idx);
              if (s0b){ bd[0] = d; bi[0] = idx; }
            }
          }
        }
      }
    }
    if (bd[KNB-1] < 3.0e37f){
      double m = 1.0e300;
      double dqx = (double)qx, dqy = (double)qy, dqz = (double)qz;
      if (cx - r > 0)      m = fmin(m, dqx - (double)(cx-r)*cinv);
      if (cx + r < GRES-1) m = fmin(m, (double)(cx+r+1)*cinv - dqx);
      if (cy - r > 0)      m = fmin(m, dqy - (double)(cy-r)*cinv);
      if (cy + r < GRES-1) m = fmin(m, (double)(cy+r+1)*cinv - dqy);
      if (cz - r > 0)      m = fmin(m, dqz - (double)(cz-r)*cinv);
      if (cz + r < GRES-1) m = fmin(m, (double)(cz+r+1)*cinv - dqz);
      // slack 1e-5 >> worst f32 d2 eval error (~5e-7): no candidate whose f32 d2
      // could beat/tie bd[15] is ever geometrically excluded
      if (m*m > (double)bd[KNB-1] + 1.0e-5) break;
    }
  }
  #pragma unroll
  for (int k=0;k<KNB;++k) ind[row*KNB + k] = bi[k];
}

// ---------------- weight packing into B-fragment order ----------------
// B-frag (mfma_f32_16x16x32_bf16): lane l holds B[ks*32 + (l>>4)*8 + j][nt*16 + (l&15)], j=0..7
__global__ __launch_bounds__(256) void pack_kernel(const float* __restrict__ src, short* __restrict__ dst){
  int f = blockIdx.x*256 + threadIdx.x;     // 0..16383
  int j  = f & 7;
  int ln = (f >> 3) & 63;
  int ks = (f >> 9) & 3;
  int nt = f >> 11;
  int k = ks*32 + ((ln >> 4) << 3) + j;
  int n = nt*16 + (ln & 15);
  dst[f] = (short)f2b(src[k*DIMF + n]);
}

// ---------------- proj: q = x@Wq, xk = x@Wk, xv = x@Wv ----------------
__global__ __launch_bounds__(256) void proj_kernel(const float* __restrict__ x, const short* __restrict__ pw,
                                                   float* __restrict__ q, float* __restrict__ xk, float* __restrict__ xv){
  __shared__ __align__(16) char Abuf[32768];
  int tid = threadIdx.x, lane = tid & 63, wv = tid >> 6;
  int r0 = blockIdx.x * 128;
  {
    int row = tid >> 1, half = tid & 1;
    const float* xr = x + (size_t)(r0 + row)*DIMF + half*64;
    #pragma unroll
    for (int i=0;i<8;++i){
      bf16x8 v;
      #pragma unroll
      for (int j=0;j<8;++j) v[j] = (short)f2b(xr[i*8 + j]);
      *(bf16x8*)(&Abuf[row*256 + ((half*128 + i*16) ^ ((row&7)<<4))]) = v;
    }
  }
  __syncthreads();
  #pragma unroll 1
  for (int w = 0; w < 3; ++w){
    const bf16x8* bw = (const bf16x8*)(pw + w*16384);
    float* dst = (w==0) ? q : (w==1) ? xk : xv;
    f32x4 acc[2][8];
    #pragma unroll
    for (int i=0;i<2;++i)
      #pragma unroll
      for (int nt=0;nt<8;++nt) acc[i][nt] = (f32x4){0.f,0.f,0.f,0.f};
    #pragma unroll
    for (int ks=0;ks<4;++ks){
      int ra = (wv*2)*16 + (lane&15);
      int rb = (wv*2+1)*16 + (lane&15);
      int cb = ks*64 + ((lane>>4)<<4);
      bf16x8 a0 = *(const bf16x8*)(&Abuf[ra*256 + (cb ^ ((ra&7)<<4))]);
      bf16x8 a1 = *(const bf16x8*)(&Abuf[rb*256 + (cb ^ ((rb&7)<<4))]);
      #pragma unroll
      for (int nt=0;nt<8;++nt){
        bf16x8 b = bw[(nt*4+ks)*64 + lane];
        acc[0][nt] = __builtin_amdgcn_mfma_f32_16x16x32_bf16(a0, b, acc[0][nt], 0, 0, 0);
        acc[1][nt] = __builtin_amdgcn_mfma_f32_16x16x32_bf16(a1, b, acc[1][nt], 0, 0, 0);
      }
    }
    #pragma unroll
    for (int i=0;i<2;++i){
      int mt = wv*2+i;
      #pragma unroll
      for (int nt=0;nt<8;++nt){
        #pragma unroll
        for (int r=0;r<4;++r){
          int grow = r0 + mt*16 + ((lane>>4)<<2) + r;
          dst[(size_t)grow*DIMF + nt*16 + (lane&15)] = acc[i][nt][r];
        }
      }
    }
  }
}

// ---------------- fused main kernel: 8 points / wg ----------------
__global__ __launch_bounds__(256) void main_kernel(
    const float* __restrict__ x, const float* __restrict__ pos,
    const float* __restrict__ pe_w1, const float* __restrict__ pe_b1, const float* __restrict__ pe_b2,
    const float* __restrict__ mid_b1, const float* __restrict__ mid_b2,
    const float* __restrict__ fin_w, const float* __restrict__ fin_b,
    const float* __restrict__ qarr, const float* __restrict__ xkarr, const float* __restrict__ xvarr,
    const int* __restrict__ ind, const short* __restrict__ pw,
    float* __restrict__ out)
{
  __shared__ __align__(16) char Abuf[32768];
  __shared__ float aggbuf[8][DIMF];
  __shared__ int indbuf[128];
  int tid = threadIdx.x;
  int lane = tid & 63;
  int wv = tid >> 6;
  int p0 = blockIdx.x * 8;

  // Phase A: t = relu(rel @ pe_w1 + pe_b1) -> Abuf (bf16, swizzled)
  {
    int row = tid >> 1, half = tid & 1;
    int pt = p0 + (row >> 4);
    int nbr = ind[pt*KNB + (row & 15)];
    if (half == 0) indbuf[row] = nbr;
    float rx = pos[pt*3+0] - pos[nbr*3+0];
    float ry = pos[pt*3+1] - pos[nbr*3+1];
    float rz = pos[pt*3+2] - pos[nbr*3+2];
    const float4* w0 = (const float4*)(pe_w1);
    const float4* w1 = (const float4*)(pe_w1 + DIMF);
    const float4* w2 = (const float4*)(pe_w1 + 2*DIMF);
    const float4* bb = (const float4*)(pe_b1);
    #pragma unroll
    for (int i=0;i<8;++i){
      int c4 = half*16 + i*2;
      float4 va0 = w0[c4], va1 = w0[c4+1];
      float4 vb0 = w1[c4], vb1 = w1[c4+1];
      float4 vc0 = w2[c4], vc1 = w2[c4+1];
      float4 vd0 = bb[c4], vd1 = bb[c4+1];
      bf16x8 v;
      float tv;
      tv = fmaf(rx,va0.x,fmaf(ry,vb0.x,fmaf(rz,vc0.x,vd0.x))); v[0]=(short)f2b(fmaxf(tv,0.f));
      tv = fmaf(rx,va0.y,fmaf(ry,vb0.y,fmaf(rz,vc0.y,vd0.y))); v[1]=(short)f2b(fmaxf(tv,0.f));
      tv = fmaf(rx,va0.z,fmaf(ry,vb0.z,fmaf(rz,vc0.z,vd0.z))); v[2]=(short)f2b(fmaxf(tv,0.f));
      tv = fmaf(rx,va0.w,fmaf(ry,vb0.w,fmaf(rz,vc0.w,vd0.w))); v[3]=(short)f2b(fmaxf(tv,0.f));
      tv = fmaf(rx,va1.x,fmaf(ry,vb1.x,fmaf(rz,vc1.x,vd1.x))); v[4]=(short)f2b(fmaxf(tv,0.f));
      tv = fmaf(rx,va1.y,fmaf(ry,vb1.y,fmaf(rz,vc1.y,vd1.y))); v[5]=(short)f2b(fmaxf(tv,0.f));
      tv = fmaf(rx,va1.z,fmaf(ry,vb1.z,fmaf(rz,vc1.z,vd1.z))); v[6]=(short)f2b(fmaxf(tv,0.f));
      tv = fmaf(rx,va1.w,fmaf(ry,vb1.w,fmaf(rz,vc1.w,vd1.w))); v[7]=(short)f2b(fmaxf(tv,0.f));
      *(bf16x8*)(&Abuf[row*256 + ((half*128 + i*16) ^ ((row&7)<<4))]) = v;
    }
  }
  __syncthreads();

  f32x4 zreg[2][8];

  // GEMM1: pe = t @ pe_w2 + pe_b2 ; then h -> Abuf, z -> zreg
  {
    const bf16x8* bw = (const bf16x8*)(pw + 3*16384);
    f32x4 acc[2][8];
    #pragma unroll
    for (int nt=0;nt<8;++nt){
      float bv = pe_b2[nt*16 + (lane&15)];
      f32x4 iv = {bv,bv,bv,bv};
      acc[0][nt] = iv; acc[1][nt] = iv;
    }
    #pragma unroll
    for (int ks=0;ks<4;++ks){
      int ra = (wv*2)*16 + (lane&15);
      int rb = (wv*2+1)*16 + (lane&15);
      int cb = ks*64 + ((lane>>4)<<4);
      bf16x8 a0 = *(const bf16x8*)(&Abuf[ra*256 + (cb ^ ((ra&7)<<4))]);
      bf16x8 a1 = *(const bf16x8*)(&Abuf[rb*256 + (cb ^ ((rb&7)<<4))]);
      #pragma unroll
      for (int nt=0;nt<8;++nt){
        bf16x8 b = bw[(nt*4+ks)*64 + lane];
        acc[0][nt] = __builtin_amdgcn_mfma_f32_16x16x32_bf16(a0, b, acc[0][nt], 0, 0, 0);
        acc[1][nt] = __builtin_amdgcn_mfma_f32_16x16x32_bf16(a1, b, acc[1][nt], 0, 0, 0);
      }
    }
    __syncthreads();   // everyone done reading t
    #pragma unroll
    for (int i=0;i<2;++i){
      int mt = wv*2+i, ptg = p0+mt;
      int nbrs[4];
      #pragma unroll
      for (int r=0;r<4;++r) nbrs[r] = indbuf[mt*16 + ((lane>>4)<<2) + r];
      #pragma unroll
      for (int nt=0;nt<8;++nt){
        int col = nt*16 + (lane&15);
        float qv = qarr[(size_t)ptg*DIMF + col];
        #pragma unroll
        for (int r=0;r<4;++r){
          float pe = acc[i][nt][r];
          float hv = qv - xkarr[(size_t)nbrs[r]*DIMF + col] + pe;
          zreg[i][nt][r] = xvarr[(size_t)nbrs[r]*DIMF + col] + pe;
          int rowg = mt*16 + ((lane>>4)<<2) + r;
          *(short*)(&Abuf[rowg*256 + ((col*2) ^ ((rowg&7)<<4))]) = (short)f2b(hv);
        }
      }
    }
  }
  __syncthreads();

  // GEMM2: u = relu(h @ mid_w1 + mid_b1) -> Abuf
  {
    const bf16x8* bw = (const bf16x8*)(pw + 4*16384);
    f32x4 acc[2][8];
    #pragma unroll
    for (int nt=0;nt<8;++nt){
      float bv = mid_b1[nt*16 + (lane&15)];
      f32x4 iv = {bv,bv,bv,bv};
      acc[0][nt] = iv; acc[1][nt] = iv;
    }
    #pragma unroll
    for (int ks=0;ks<4;++ks){
      int ra = (wv*2)*16 + (lane&15);
      int rb = (wv*2+1)*16 + (lane&15);
      int cb = ks*64 + ((lane>>4)<<4);
      bf16x8 a0 = *(const bf16x8*)(&Abuf[ra*256 + (cb ^ ((ra&7)<<4))]);
      bf16x8 a1 = *(const bf16x8*)(&Abuf[rb*256 + (cb ^ ((rb&7)<<4))]);
      #pragma unroll
      for (int nt=0;nt<8;++nt){
        bf16x8 b = bw[(nt*4+ks)*64 + lane];
        acc[0][nt] = __builtin_amdgcn_mfma_f32_16x16x32_bf16(a0, b, acc[0][nt], 0, 0, 0);
        acc[1][nt] = __builtin_amdgcn_mfma_f32_16x16x32_bf16(a1, b, acc[1][nt], 0, 0, 0);
      }
    }
    __syncthreads();   // everyone done reading h
    #pragma unroll
    for (int i=0;i<2;++i){
      int mt = wv*2+i;
      #pragma unroll
      for (int nt=0;nt<8;++nt){
        int col = nt*16 + (lane&15);
        #pragma unroll
        for (int r=0;r<4;++r){
          int rowg = mt*16 + ((lane>>4)<<2) + r;
          *(short*)(&Abuf[rowg*256 + ((col*2) ^ ((rowg&7)<<4))]) = (short)f2b(fmaxf(acc[i][nt][r], 0.f));
        }
      }
    }
  }
  __syncthreads();

  // GEMM3: y = u @ mid_w2 + mid_b2 ; softmax over K; agg = sum(y_sm * z)
  {
    const bf16x8* bw = (const bf16x8*)(pw + 5*16384);
    f32x4 acc[2][8];
    #pragma unroll
    for (int nt=0;nt<8;++nt){
      float bv = mid_b2[nt*16 + (lane&15)];
      f32x4 iv = {bv,bv,bv,bv};
      acc[0][nt] = iv; acc[1][nt] = iv;
    }
    #pragma unroll
    for (int ks=0;ks<4;++ks){
      int ra = (wv*2)*16 + (lane&15);
      int rb = (wv*2+1)*16 + (lane&15);
      int cb = ks*64 + ((lane>>4)<<4);
      bf16x8 a0 = *(const bf16x8*)(&Abuf[ra*256 + (cb ^ ((ra&7)<<4))]);
      bf16x8 a1 = *(const bf16x8*)(&Abuf[rb*256 + (cb ^ ((rb&7)<<4))]);
      #pragma unroll
      for (int nt=0;nt<8;++nt){
        bf16x8 b = bw[(nt*4+ks)*64 + lane];
        acc[0][nt] = __builtin_amdgcn_mfma_f32_16x16x32_bf16(a0, b, acc[0][nt], 0, 0, 0);
        acc[1][nt] = __builtin_amdgcn_mfma_f32_16x16x32_bf16(a1, b, acc[1][nt], 0, 0, 0);
      }
    }
    const float invS = 0.08838834764831843f;   // 1/sqrt(128)
    #pragma unroll
    for (int i=0;i<2;++i){
      int mt = wv*2+i;
      #pragma unroll
      for (int nt=0;nt<8;++nt){
        f32x4 y = acc[i][nt];
        float mx = fmaxf(fmaxf(y[0],y[1]), fmaxf(y[2],y[3]));
        mx = fmaxf(mx, __shfl_xor(mx, 16, 64));
        mx = fmaxf(mx, __shfl_xor(mx, 32, 64));
        float e0 = __expf((y[0]-mx)*invS);
        float e1 = __expf((y[1]-mx)*invS);
        float e2 = __expf((y[2]-mx)*invS);
        float e3 = __expf((y[3]-mx)*invS);
        float ssum = e0+e1+e2+e3;
        ssum += __shfl_xor(ssum, 16, 64);
        ssum += __shfl_xor(ssum, 32, 64);
        f32x4 zz = zreg[i][nt];
        float ps = (e0*zz[0] + e1*zz[1] + e2*zz[2] + e3*zz[3]) / ssum;
        ps += __shfl_xor(ps, 16, 64);
        ps += __shfl_xor(ps, 32, 64);
        if (lane < 16) aggbuf[mt][nt*16 + lane] = ps;
      }
    }
  }
  __syncthreads();

  // Final: out = agg @ fin_w + fin_b + x
  {
    int c = tid & 127;
    int pg = tid >> 7;  // 0 or 1 -> points pg*4 .. pg*4+3
    float fb = fin_b[c];
    float a0 = fb, a1 = fb, a2 = fb, a3 = fb;
    for (int d = 0; d < DIMF; ++d){
      float wvv = fin_w[d*DIMF + c];
      a0 = fmaf(aggbuf[pg*4+0][d], wvv, a0);
      a1 = fmaf(aggbuf[pg*4+1][d], wvv, a1);
      a2 = fmaf(aggbuf[pg*4+2][d], wvv, a2);
      a3 = fmaf(aggbuf[pg*4+3][d], wvv, a3);
    }
    size_t base0 = (size_t)(p0 + pg*4)*DIMF + c;
    out[base0 + 0*DIMF] = a0 + x[base0 + 0*DIMF];
    out[base0 + 1*DIMF] = a1 + x[base0 + 1*DIMF];
    out[base0 + 2*DIMF] = a2 + x[base0 + 2*DIMF];
    out[base0 + 3*DIMF] = a3 + x[base0 + 3*DIMF];
  }
}

extern "C" void kernel_launch(void* const* d_in, const int* in_sizes, int n_in,
                              void* d_out, int out_size, void* d_ws, size_t ws_size,
                              hipStream_t stream)
{
  (void)in_sizes; (void)n_in; (void)out_size; (void)ws_size;
  const float* x      = (const float*)d_in[0];
  const float* pos    = (const float*)d_in[1];
  const float* Wq     = (const float*)d_in[2];
  const float* Wk     = (const float*)d_in[3];
  const float* Wv     = (const float*)d_in[4];
  const float* mid_w1 = (const float*)d_in[5];
  const float* mid_b1 = (const float*)d_in[6];
  const float* mid_w2 = (const float*)d_in[7];
  const float* mid_b2 = (const float*)d_in[8];
  const float* pe_w1  = (const float*)d_in[9];
  const float* pe_b1  = (const float*)d_in[10];
  const float* pe_w2  = (const float*)d_in[11];
  const float* pe_b2  = (const float*)d_in[12];
  const float* fin_w  = (const float*)d_in[13];
  const float* fin_b  = (const float*)d_in[14];
  float* out = (float*)d_out;
  char* ws = (char*)d_ws;

  int*    cellcnt = (int*)   (ws + 0);         //  16 KB
  int*    starts  = (int*)   (ws + 16384);     //  16 KB
  int*    fillp   = (int*)   (ws + 32768);     //  16 KB
  int*    pidx    = (int*)   (ws + 49152);     //  64 KB
  float4* pos4    = (float4*)(ws + 114688);    // 256 KB
  int*    ind     = (int*)   (ws + 376832);    //   1 MB
  short*  pw      = (short*) (ws + 1425408);   // 192 KB (6 packed 128x128 bf16 weights)
  float*  qarr    = (float*) (ws + 1622016);   //   8 MB
  float*  xkarr   = (float*) (ws + 10010624);  //   8 MB
  float*  xvarr   = (float*) (ws + 18399232);  //   8 MB  (end ~25.6 MB)

  hipMemsetAsync(cellcnt, 0, NCELL*sizeof(int), stream);
  count_kernel  <<<N_PTS/256, 256, 0, stream>>>(pos, cellcnt);
  scan_kernel   <<<1,         256, 0, stream>>>(cellcnt, starts, fillp);
  scatter_kernel<<<N_PTS/256, 256, 0, stream>>>(pos, fillp, pos4, pidx);
  knn_query     <<<N_PTS/256, 256, 0, stream>>>(pos4, pidx, starts, cellcnt, ind);

  pack_kernel<<<64, 256, 0, stream>>>(Wq,     pw + 0*16384);
  pack_kernel<<<64, 256, 0, stream>>>(Wk,     pw + 1*16384);
  pack_kernel<<<64, 256, 0, stream>>>(Wv,     pw + 2*16384);
  pack_kernel<<<64, 256, 0, stream>>>(pe_w2,  pw + 3*16384);
  pack_kernel<<<64, 256, 0, stream>>>(mid_w1, pw + 4*16384);
  pack_kernel<<<64, 256, 0, stream>>>(mid_w2, pw + 5*16384);

  proj_kernel<<<N_PTS/128, 256, 0, stream>>>(x, pw, qarr, xkarr, xvarr);

  main_kernel<<<N_PTS/8, 256, 0, stream>>>(x, pos, pe_w1, pe_b1, pe_b2, mid_b1, mid_b2,
                                           fin_w, fin_b, qarr, xkarr, xvarr, ind, pw, out);
}

// Round 4
// 546.340 us; speedup vs baseline: 1.3265x; 1.3265x over previous
//
#include <hip/hip_runtime.h>
#include <hip/hip_bf16.h>

#define N_PTS 16384
#define DIMF  128
#define KNB   16
#define GRES  16
#define NCELL (GRES*GRES*GRES)

typedef __attribute__((ext_vector_type(8))) short bf16x8;
typedef __attribute__((ext_vector_type(4))) float f32x4;

__device__ __forceinline__ unsigned short f2b(float f){
  unsigned int u = __float_as_uint(f);
  u = u + 0x7fffu + ((u >> 16) & 1u);
  return (unsigned short)(u >> 16);
}

// ---------------- KNN: grid build ----------------
__global__ __launch_bounds__(256) void count_kernel(const float* __restrict__ pos, int* __restrict__ cnt){
  int i = blockIdx.x*256 + threadIdx.x;
  float px = pos[i*3+0], py = pos[i*3+1], pz = pos[i*3+2];
  int cx = min(GRES-1, max(0,(int)(px*(float)GRES)));
  int cy = min(GRES-1, max(0,(int)(py*(float)GRES)));
  int cz = min(GRES-1, max(0,(int)(pz*(float)GRES)));
  atomicAdd(&cnt[(cz*GRES+cy)*GRES+cx], 1);
}

__global__ __launch_bounds__(256) void scan_kernel(const int* __restrict__ cnt, int* __restrict__ starts, int* __restrict__ fillp){
  __shared__ int part[256];
  int t = threadIdx.x;
  int loc[16];
  int s = 0;
  #pragma unroll
  for (int i=0;i<16;++i){ loc[i] = s; s += cnt[t*16+i]; }
  part[t] = s;
  __syncthreads();
  if (t == 0){
    int acc = 0;
    for (int i=0;i<256;++i){ int tmp = part[i]; part[i] = acc; acc += tmp; }
  }
  __syncthreads();
  int b = part[t];
  #pragma unroll
  for (int i=0;i<16;++i){ int v = b + loc[i]; starts[t*16+i] = v; fillp[t*16+i] = v; }
}

// sq stored numpy-style: ((x*x + y*y) + z*z), each op separately f32-rounded (no contraction)
__global__ __launch_bounds__(256) void scatter_kernel(const float* __restrict__ pos, int* __restrict__ fillp,
                                                      float4* __restrict__ pos4, int* __restrict__ pidx){
  int i = blockIdx.x*256 + threadIdx.x;
  float px = pos[i*3+0], py = pos[i*3+1], pz = pos[i*3+2];
  int cx = min(GRES-1, max(0,(int)(px*(float)GRES)));
  int cy = min(GRES-1, max(0,(int)(py*(float)GRES)));
  int cz = min(GRES-1, max(0,(int)(pz*(float)GRES)));
  int c = (cz*GRES+cy)*GRES+cx;
  float sq = __fadd_rn(__fadd_rn(__fmul_rn(px,px), __fmul_rn(py,py)), __fmul_rn(pz,pz));
  int s = atomicAdd(&fillp[c], 1);
  pos4[s] = make_float4(px, py, pz, sq);
  pidx[s] = i;
}

// 16 lanes per point. Exact top-16 by (d2, idx) lex, d2 replicating numpy float32
// bit-exactly (identical arithmetic to the passing round). Candidates are
// partitioned across the 16 lanes by a uniform stride-16 counter over the fixed
// ring-order enumeration stream; each lane keeps a local lex-sorted top-16;
// final exact 16-way merge via shuffle lex-min, 16 rounds.
__global__ __launch_bounds__(256) void knn_query(const float4* __restrict__ pos4, const int* __restrict__ pidx,
                                                 const int* __restrict__ starts, const int* __restrict__ cnt,
                                                 int* __restrict__ ind){
  int tid = threadIdx.x;
  int sub = tid & 15;            // lane within the 16-lane group
  int grp = tid >> 4;            // group within block: 0..15
  int t = blockIdx.x*16 + grp;   // slot in sorted point array
  float4 qp = pos4[t];
  int row = pidx[t];
  float qx = qp.x, qy = qp.y, qz = qp.z, qsq = qp.w;
  int cx = min(GRES-1, max(0,(int)(qx*(float)GRES)));
  int cy = min(GRES-1, max(0,(int)(qy*(float)GRES)));
  int cz = min(GRES-1, max(0,(int)(qz*(float)GRES)));
  float bd[KNB]; int bi[KNB];
  #pragma unroll
  for (int k=0;k<KNB;++k){ bd[k] = 3.0e38f; bi[k] = 0x7fffffff; }
  const double cinv = 1.0/(double)GRES;   // exact (power of 2)
  int pctr = 0;                  // uniform candidate counter (same in all lanes)
  for (int r = 0; r < GRES; ++r){
    int zlo = max(0, cz-r), zhi = min(GRES-1, cz+r);
    int ylo = max(0, cy-r), yhi = min(GRES-1, cy+r);
    int xlo = max(0, cx-r), xhi = min(GRES-1, cx+r);
    for (int zz = zlo; zz <= zhi; ++zz){
      for (int yy = ylo; yy <= yhi; ++yy){
        for (int xx = xlo; xx <= xhi; ++xx){
          int ring = max(abs(zz-cz), max(abs(yy-cy), abs(xx-cx)));
          if (ring != r) continue;
          int c = (zz*GRES+yy)*GRES+xx;
          int s0 = starts[c], n = cnt[c];
          int off = (sub - pctr) & 15;
          for (int s = s0 + off; s < s0 + n; s += 16){
            float4 pc = pos4[s];
            int idx = pidx[s];
            float dot = __fmaf_rn(qz, pc.z, __fmaf_rn(qy, pc.y, __fmul_rn(qx, pc.x)));
            float d   = __fsub_rn(__fadd_rn(qsq, pc.w), __fmul_rn(2.0f, dot));
            bool adm = (d < bd[KNB-1]) || (d == bd[KNB-1] && idx < bi[KNB-1]);
            if (adm){
              #pragma unroll
              for (int p = KNB-1; p >= 1; --p){
                float pd = bd[p-1]; int pi = bi[p-1];
                bool sh  = (pd > d) || (pd == d && pi > idx);
                bool ins = (!sh) && ((bd[p] > d) || (bd[p] == d && bi[p] > idx));
                bd[p] = sh ? pd : (ins ? d   : bd[p]);
                bi[p] = sh ? pi : (ins ? idx : bi[p]);
              }
              bool s0b = (bd[0] > d) || (bd[0] == d && bi[0] > idx);
              if (s0b){ bd[0] = d; bi[0] = idx; }
            }
          }
          pctr += n;
        }
      }
    }
    // Conservative group bound: merged 16th-best <= max over the 16 lanes of each
    // lane's best (16 distinct candidates). Lanes with empty lists contribute +inf.
    float B = bd[0];
    B = fmaxf(B, __shfl_xor(B, 1, 64));
    B = fmaxf(B, __shfl_xor(B, 2, 64));
    B = fmaxf(B, __shfl_xor(B, 4, 64));
    B = fmaxf(B, __shfl_xor(B, 8, 64));
    if (B < 3.0e37f){
      double m = 1.0e300;
      double dqx = (double)qx, dqy = (double)qy, dqz = (double)qz;
      if (cx - r > 0)      m = fmin(m, dqx - (double)(cx-r)*cinv);
      if (cx + r < GRES-1) m = fmin(m, (double)(cx+r+1)*cinv - dqx);
      if (cy - r > 0)      m = fmin(m, dqy - (double)(cy-r)*cinv);
      if (cy + r < GRES-1) m = fmin(m, (double)(cy+r+1)*cinv - dqy);
      if (cz - r > 0)      m = fmin(m, dqz - (double)(cz-r)*cinv);
      if (cz + r < GRES-1) m = fmin(m, (double)(cz+r+1)*cinv - dqz);
      // slack 1e-5 >> worst f32 d2 eval error (~5e-7)
      if (m*m > (double)B + 1.0e-5) break;
    }
  }
  // exact 16-way merge of the 16 sorted lists: 16 rounds of lex-min reduce + winner shift
  int res_i = 0x7fffffff;
  for (int k = 0; k < KNB; ++k){
    float md = bd[0]; int mi = bi[0];
    #pragma unroll
    for (int o = 1; o < 16; o <<= 1){
      float od = __shfl_xor(md, o, 64);
      int   oi = __shfl_xor(mi, o, 64);
      bool take = (od < md) || (od == md && oi < mi);
      md = take ? od : md;
      mi = take ? oi : mi;
    }
    if (sub == k) res_i = mi;
    bool winner = (bd[0] == md) && (bi[0] == mi);
    if (winner){
      #pragma unroll
      for (int p = 0; p < KNB-1; ++p){ bd[p] = bd[p+1]; bi[p] = bi[p+1]; }
      bd[KNB-1] = 3.0e38f; bi[KNB-1] = 0x7fffffff;
    }
  }
  ind[row*KNB + sub] = res_i;
}

// ---------------- weight packing into B-fragment order ----------------
// B-frag (mfma_f32_16x16x32_bf16): lane l holds B[ks*32 + (l>>4)*8 + j][nt*16 + (l&15)], j=0..7
__global__ __launch_bounds__(256) void pack_kernel(const float* __restrict__ src, short* __restrict__ dst){
  int f = blockIdx.x*256 + threadIdx.x;     // 0..16383
  int j  = f & 7;
  int ln = (f >> 3) & 63;
  int ks = (f >> 9) & 3;
  int nt = f >> 11;
  int k = ks*32 + ((ln >> 4) << 3) + j;
  int n = nt*16 + (ln & 15);
  dst[f] = (short)f2b(src[k*DIMF + n]);
}

// ---------------- proj: q = x@Wq, xk = x@Wk, xv = x@Wv ----------------
__global__ __launch_bounds__(256) void proj_kernel(const float* __restrict__ x, const short* __restrict__ pw,
                                                   float* __restrict__ q, float* __restrict__ xk, float* __restrict__ xv){
  __shared__ __align__(16) char Abuf[32768];
  int tid = threadIdx.x, lane = tid & 63, wv = tid >> 6;
  int r0 = blockIdx.x * 128;
  {
    int row = tid >> 1, half = tid & 1;
    const float* xr = x + (size_t)(r0 + row)*DIMF + half*64;
    #pragma unroll
    for (int i=0;i<8;++i){
      bf16x8 v;
      #pragma unroll
      for (int j=0;j<8;++j) v[j] = (short)f2b(xr[i*8 + j]);
      *(bf16x8*)(&Abuf[row*256 + ((half*128 + i*16) ^ ((row&7)<<4))]) = v;
    }
  }
  __syncthreads();
  #pragma unroll 1
  for (int w = 0; w < 3; ++w){
    const bf16x8* bw = (const bf16x8*)(pw + w*16384);
    float* dst = (w==0) ? q : (w==1) ? xk : xv;
    f32x4 acc[2][8];
    #pragma unroll
    for (int i=0;i<2;++i)
      #pragma unroll
      for (int nt=0;nt<8;++nt) acc[i][nt] = (f32x4){0.f,0.f,0.f,0.f};
    #pragma unroll
    for (int ks=0;ks<4;++ks){
      int ra = (wv*2)*16 + (lane&15);
      int rb = (wv*2+1)*16 + (lane&15);
      int cb = ks*64 + ((lane>>4)<<4);
      bf16x8 a0 = *(const bf16x8*)(&Abuf[ra*256 + (cb ^ ((ra&7)<<4))]);
      bf16x8 a1 = *(const bf16x8*)(&Abuf[rb*256 + (cb ^ ((rb&7)<<4))]);
      #pragma unroll
      for (int nt=0;nt<8;++nt){
        bf16x8 b = bw[(nt*4+ks)*64 + lane];
        acc[0][nt] = __builtin_amdgcn_mfma_f32_16x16x32_bf16(a0, b, acc[0][nt], 0, 0, 0);
        acc[1][nt] = __builtin_amdgcn_mfma_f32_16x16x32_bf16(a1, b, acc[1][nt], 0, 0, 0);
      }
    }
    #pragma unroll
    for (int i=0;i<2;++i){
      int mt = wv*2+i;
      #pragma unroll
      for (int nt=0;nt<8;++nt){
        #pragma unroll
        for (int r=0;r<4;++r){
          int grow = r0 + mt*16 + ((lane>>4)<<2) + r;
          dst[(size_t)grow*DIMF + nt*16 + (lane&15)] = acc[i][nt][r];
        }
      }
    }
  }
}

// ---------------- fused main kernel: 8 points / wg ----------------
__global__ __launch_bounds__(256) void main_kernel(
    const float* __restrict__ x, const float* __restrict__ pos,
    const float* __restrict__ pe_w1, const float* __restrict__ pe_b1, const float* __restrict__ pe_b2,
    const float* __restrict__ mid_b1, const float* __restrict__ mid_b2,
    const float* __restrict__ fin_w, const float* __restrict__ fin_b,
    const float* __restrict__ qarr, const float* __restrict__ xkarr, const float* __restrict__ xvarr,
    const int* __restrict__ ind, const short* __restrict__ pw,
    float* __restrict__ out)
{
  __shared__ __align__(16) char Abuf[32768];
  __shared__ float aggbuf[8][DIMF];
  __shared__ int indbuf[128];
  int tid = threadIdx.x;
  int lane = tid & 63;
  int wv = tid >> 6;
  int p0 = blockIdx.x * 8;

  // Phase A: t = relu(rel @ pe_w1 + pe_b1) -> Abuf (bf16, swizzled)
  {
    int row = tid >> 1, half = tid & 1;
    int pt = p0 + (row >> 4);
    int nbr = ind[pt*KNB + (row & 15)];
    if (half == 0) indbuf[row] = nbr;
    float rx = pos[pt*3+0] - pos[nbr*3+0];
    float ry = pos[pt*3+1] - pos[nbr*3+1];
    float rz = pos[pt*3+2] - pos[nbr*3+2];
    const float4* w0 = (const float4*)(pe_w1);
    const float4* w1 = (const float4*)(pe_w1 + DIMF);
    const float4* w2 = (const float4*)(pe_w1 + 2*DIMF);
    const float4* bb = (const float4*)(pe_b1);
    #pragma unroll
    for (int i=0;i<8;++i){
      int c4 = half*16 + i*2;
      float4 va0 = w0[c4], va1 = w0[c4+1];
      float4 vb0 = w1[c4], vb1 = w1[c4+1];
      float4 vc0 = w2[c4], vc1 = w2[c4+1];
      float4 vd0 = bb[c4], vd1 = bb[c4+1];
      bf16x8 v;
      float tv;
      tv = fmaf(rx,va0.x,fmaf(ry,vb0.x,fmaf(rz,vc0.x,vd0.x))); v[0]=(short)f2b(fmaxf(tv,0.f));
      tv = fmaf(rx,va0.y,fmaf(ry,vb0.y,fmaf(rz,vc0.y,vd0.y))); v[1]=(short)f2b(fmaxf(tv,0.f));
      tv = fmaf(rx,va0.z,fmaf(ry,vb0.z,fmaf(rz,vc0.z,vd0.z))); v[2]=(short)f2b(fmaxf(tv,0.f));
      tv = fmaf(rx,va0.w,fmaf(ry,vb0.w,fmaf(rz,vc0.w,vd0.w))); v[3]=(short)f2b(fmaxf(tv,0.f));
      tv = fmaf(rx,va1.x,fmaf(ry,vb1.x,fmaf(rz,vc1.x,vd1.x))); v[4]=(short)f2b(fmaxf(tv,0.f));
      tv = fmaf(rx,va1.y,fmaf(ry,vb1.y,fmaf(rz,vc1.y,vd1.y))); v[5]=(short)f2b(fmaxf(tv,0.f));
      tv = fmaf(rx,va1.z,fmaf(ry,vb1.z,fmaf(rz,vc1.z,vd1.z))); v[6]=(short)f2b(fmaxf(tv,0.f));
      tv = fmaf(rx,va1.w,fmaf(ry,vb1.w,fmaf(rz,vc1.w,vd1.w))); v[7]=(short)f2b(fmaxf(tv,0.f));
      *(bf16x8*)(&Abuf[row*256 + ((half*128 + i*16) ^ ((row&7)<<4))]) = v;
    }
  }
  __syncthreads();

  f32x4 zreg[2][8];

  // GEMM1: pe = t @ pe_w2 + pe_b2 ; then h -> Abuf, z -> zreg
  {
    const bf16x8* bw = (const bf16x8*)(pw + 3*16384);
    f32x4 acc[2][8];
    #pragma unroll
    for (int nt=0;nt<8;++nt){
      float bv = pe_b2[nt*16 + (lane&15)];
      f32x4 iv = {bv,bv,bv,bv};
      acc[0][nt] = iv; acc[1][nt] = iv;
    }
    #pragma unroll
    for (int ks=0;ks<4;++ks){
      int ra = (wv*2)*16 + (lane&15);
      int rb = (wv*2+1)*16 + (lane&15);
      int cb = ks*64 + ((lane>>4)<<4);
      bf16x8 a0 = *(const bf16x8*)(&Abuf[ra*256 + (cb ^ ((ra&7)<<4))]);
      bf16x8 a1 = *(const bf16x8*)(&Abuf[rb*256 + (cb ^ ((rb&7)<<4))]);
      #pragma unroll
      for (int nt=0;nt<8;++nt){
        bf16x8 b = bw[(nt*4+ks)*64 + lane];
        acc[0][nt] = __builtin_amdgcn_mfma_f32_16x16x32_bf16(a0, b, acc[0][nt], 0, 0, 0);
        acc[1][nt] = __builtin_amdgcn_mfma_f32_16x16x32_bf16(a1, b, acc[1][nt], 0, 0, 0);
      }
    }
    __syncthreads();   // everyone done reading t
    #pragma unroll
    for (int i=0;i<2;++i){
      int mt = wv*2+i, ptg = p0+mt;
      int nbrs[4];
      #pragma unroll
      for (int r=0;r<4;++r) nbrs[r] = indbuf[mt*16 + ((lane>>4)<<2) + r];
      #pragma unroll
      for (int nt=0;nt<8;++nt){
        int col = nt*16 + (lane&15);
        float qv = qarr[(size_t)ptg*DIMF + col];
        #pragma unroll
        for (int r=0;r<4;++r){
          float pe = acc[i][nt][r];
          float hv = qv - xkarr[(size_t)nbrs[r]*DIMF + col] + pe;
          zreg[i][nt][r] = xvarr[(size_t)nbrs[r]*DIMF + col] + pe;
          int rowg = mt*16 + ((lane>>4)<<2) + r;
          *(short*)(&Abuf[rowg*256 + ((col*2) ^ ((rowg&7)<<4))]) = (short)f2b(hv);
        }
      }
    }
  }
  __syncthreads();

  // GEMM2: u = relu(h @ mid_w1 + mid_b1) -> Abuf
  {
    const bf16x8* bw = (const bf16x8*)(pw + 4*16384);
    f32x4 acc[2][8];
    #pragma unroll
    for (int nt=0;nt<8;++nt){
      float bv = mid_b1[nt*16 + (lane&15)];
      f32x4 iv = {bv,bv,bv,bv};
      acc[0][nt] = iv; acc[1][nt] = iv;
    }
    #pragma unroll
    for (int ks=0;ks<4;++ks){
      int ra = (wv*2)*16 + (lane&15);
      int rb = (wv*2+1)*16 + (lane&15);
      int cb = ks*64 + ((lane>>4)<<4);
      bf16x8 a0 = *(const bf16x8*)(&Abuf[ra*256 + (cb ^ ((ra&7)<<4))]);
      bf16x8 a1 = *(const bf16x8*)(&Abuf[rb*256 + (cb ^ ((rb&7)<<4))]);
      #pragma unroll
      for (int nt=0;nt<8;++nt){
        bf16x8 b = bw[(nt*4+ks)*64 + lane];
        acc[0][nt] = __builtin_amdgcn_mfma_f32_16x16x32_bf16(a0, b, acc[0][nt], 0, 0, 0);
        acc[1][nt] = __builtin_amdgcn_mfma_f32_16x16x32_bf16(a1, b, acc[1][nt], 0, 0, 0);
      }
    }
    __syncthreads();   // everyone done reading h
    #pragma unroll
    for (int i=0;i<2;++i){
      int mt = wv*2+i;
      #pragma unroll
      for (int nt=0;nt<8;++nt){
        int col = nt*16 + (lane&15);
        #pragma unroll
        for (int r=0;r<4;++r){
          int rowg = mt*16 + ((lane>>4)<<2) + r;
          *(short*)(&Abuf[rowg*256 + ((col*2) ^ ((rowg&7)<<4))]) = (short)f2b(fmaxf(acc[i][nt][r], 0.f));
        }
      }
    }
  }
  __syncthreads();

  // GEMM3: y = u @ mid_w2 + mid_b2 ; softmax over K; agg = sum(y_sm * z)
  {
    const bf16x8* bw = (const bf16x8*)(pw + 5*16384);
    f32x4 acc[2][8];
    #pragma unroll
    for (int nt=0;nt<8;++nt){
      float bv = mid_b2[nt*16 + (lane&15)];
      f32x4 iv = {bv,bv,bv,bv};
      acc[0][nt] = iv; acc[1][nt] = iv;
    }
    #pragma unroll
    for (int ks=0;ks<4;++ks){
      int ra = (wv*2)*16 + (lane&15);
      int rb = (wv*2+1)*16 + (lane&15);
      int cb = ks*64 + ((lane>>4)<<4);
      bf16x8 a0 = *(const bf16x8*)(&Abuf[ra*256 + (cb ^ ((ra&7)<<4))]);
      bf16x8 a1 = *(const bf16x8*)(&Abuf[rb*256 + (cb ^ ((rb&7)<<4))]);
      #pragma unroll
      for (int nt=0;nt<8;++nt){
        bf16x8 b = bw[(nt*4+ks)*64 + lane];
        acc[0][nt] = __builtin_amdgcn_mfma_f32_16x16x32_bf16(a0, b, acc[0][nt], 0, 0, 0);
        acc[1][nt] = __builtin_amdgcn_mfma_f32_16x16x32_bf16(a1, b, acc[1][nt], 0, 0, 0);
      }
    }
    const float invS = 0.08838834764831843f;   // 1/sqrt(128)
    #pragma unroll
    for (int i=0;i<2;++i){
      int mt = wv*2+i;
      #pragma unroll
      for (int nt=0;nt<8;++nt){
        f32x4 y = acc[i][nt];
        float mx = fmaxf(fmaxf(y[0],y[1]), fmaxf(y[2],y[3]));
        mx = fmaxf(mx, __shfl_xor(mx, 16, 64));
        mx = fmaxf(mx, __shfl_xor(mx, 32, 64));
        float e0 = __expf((y[0]-mx)*invS);
        float e1 = __expf((y[1]-mx)*invS);
        float e2 = __expf((y[2]-mx)*invS);
        float e3 = __expf((y[3]-mx)*invS);
        float ssum = e0+e1+e2+e3;
        ssum += __shfl_xor(ssum, 16, 64);
        ssum += __shfl_xor(ssum, 32, 64);
        f32x4 zz = zreg[i][nt];
        float ps = (e0*zz[0] + e1*zz[1] + e2*zz[2] + e3*zz[3]) / ssum;
        ps += __shfl_xor(ps, 16, 64);
        ps += __shfl_xor(ps, 32, 64);
        if (lane < 16) aggbuf[mt][nt*16 + lane] = ps;
      }
    }
  }
  __syncthreads();

  // Final: out = agg @ fin_w + fin_b + x
  {
    int c = tid & 127;
    int pg = tid >> 7;  // 0 or 1 -> points pg*4 .. pg*4+3
    float fb = fin_b[c];
    float a0 = fb, a1 = fb, a2 = fb, a3 = fb;
    for (int d = 0; d < DIMF; ++d){
      float wvv = fin_w[d*DIMF + c];
      a0 = fmaf(aggbuf[pg*4+0][d], wvv, a0);
      a1 = fmaf(aggbuf[pg*4+1][d], wvv, a1);
      a2 = fmaf(aggbuf[pg*4+2][d], wvv, a2);
      a3 = fmaf(aggbuf[pg*4+3][d], wvv, a3);
    }
    size_t base0 = (size_t)(p0 + pg*4)*DIMF + c;
    out[base0 + 0*DIMF] = a0 + x[base0 + 0*DIMF];
    out[base0 + 1*DIMF] = a1 + x[base0 + 1*DIMF];
    out[base0 + 2*DIMF] = a2 + x[base0 + 2*DIMF];
    out[base0 + 3*DIMF] = a3 + x[base0 + 3*DIMF];
  }
}

extern "C" void kernel_launch(void* const* d_in, const int* in_sizes, int n_in,
                              void* d_out, int out_size, void* d_ws, size_t ws_size,
                              hipStream_t stream)
{
  (void)in_sizes; (void)n_in; (void)out_size; (void)ws_size;
  const float* x      = (const float*)d_in[0];
  const float* pos    = (const float*)d_in[1];
  const float* Wq     = (const float*)d_in[2];
  const float* Wk     = (const float*)d_in[3];
  const float* Wv     = (const float*)d_in[4];
  const float* mid_w1 = (const float*)d_in[5];
  const float* mid_b1 = (const float*)d_in[6];
  const float* mid_w2 = (const float*)d_in[7];
  const float* mid_b2 = (const float*)d_in[8];
  const float* pe_w1  = (const float*)d_in[9];
  const float* pe_b1  = (const float*)d_in[10];
  const float* pe_w2  = (const float*)d_in[11];
  const float* pe_b2  = (const float*)d_in[12];
  const float* fin_w  = (const float*)d_in[13];
  const float* fin_b  = (const float*)d_in[14];
  float* out = (float*)d_out;
  char* ws = (char*)d_ws;

  int*    cellcnt = (int*)   (ws + 0);         //  16 KB
  int*    starts  = (int*)   (ws + 16384);     //  16 KB
  int*    fillp   = (int*)   (ws + 32768);     //  16 KB
  int*    pidx    = (int*)   (ws + 49152);     //  64 KB
  float4* pos4    = (float4*)(ws + 114688);    // 256 KB
  int*    ind     = (int*)   (ws + 376832);    //   1 MB
  short*  pw      = (short*) (ws + 1425408);   // 192 KB (6 packed 128x128 bf16 weights)
  float*  qarr    = (float*) (ws + 1622016);   //   8 MB
  float*  xkarr   = (float*) (ws + 10010624);  //   8 MB
  float*  xvarr   = (float*) (ws + 18399232);  //   8 MB  (end ~25.6 MB)

  hipMemsetAsync(cellcnt, 0, NCELL*sizeof(int), stream);
  count_kernel  <<<N_PTS/256, 256, 0, stream>>>(pos, cellcnt);
  scan_kernel   <<<1,         256, 0, stream>>>(cellcnt, starts, fillp);
  scatter_kernel<<<N_PTS/256, 256, 0, stream>>>(pos, fillp, pos4, pidx);
  knn_query     <<<N_PTS/16,  256, 0, stream>>>(pos4, pidx, starts, cellcnt, ind);

  pack_kernel<<<64, 256, 0, stream>>>(Wq,     pw + 0*16384);
  pack_kernel<<<64, 256, 0, stream>>>(Wk,     pw + 1*16384);
  pack_kernel<<<64, 256, 0, stream>>>(Wv,     pw + 2*16384);
  pack_kernel<<<64, 256, 0, stream>>>(pe_w2,  pw + 3*16384);
  pack_kernel<<<64, 256, 0, stream>>>(mid_w1, pw + 4*16384);
  pack_kernel<<<64, 256, 0, stream>>>(mid_w2, pw + 5*16384);

  proj_kernel<<<N_PTS/128, 256, 0, stream>>>(x, pw, qarr, xkarr, xvarr);

  main_kernel<<<N_PTS/8, 256, 0, stream>>>(x, pos, pe_w1, pe_b1, pe_b2, mid_b1, mid_b2,
                                           fin_w, fin_b, qarr, xkarr, xvarr, ind, pw, out);
}